// Round 1
// baseline (880.590 us; speedup 1.0000x reference)
//
#include <hip/hip_runtime.h>
#include <hip/hip_bf16.h>

#define BSZ   4
#define CDIM  512
#define NDIM  512
#define SDIM  64
#define LEN   8192
#define GCH   16            // chunks per (b,n)
#define TCH   (LEN / GCH)   // 512 steps per chunk

// ---------------------------------------------------------------------------
// Generic fp32 GEMM: Y[b][m][l] = sum_k A[m][k] * X[b][k][l]
// M = K = 512, Lcols = 8192, batch via blockIdx.z. 64x64 tile, BK=16, 4x4/thread.
// ---------------------------------------------------------------------------
__global__ __launch_bounds__(256) void gemm512(const float* __restrict__ A,
                                               const float* __restrict__ X,
                                               float* __restrict__ Y) {
    __shared__ __align__(16) float As[16][64];  // As[k][m]
    __shared__ __align__(16) float Bs[16][64];  // Bs[k][l]
    const int b  = blockIdx.z;
    const int m0 = blockIdx.y << 6;
    const int l0 = blockIdx.x << 6;
    const float* Xb = X + ((size_t)b * CDIM * LEN);
    float*       Yb = Y + ((size_t)b * CDIM * LEN);
    const int t  = threadIdx.x;
    const int tx = t & 15, ty = t >> 4;
    const int am = t >> 2, ak = (t & 3) << 2;   // A loader: row m, 4 k's
    const int bk = t >> 4, bl = (t & 15) << 2;  // X loader: row k, 4 l's

    float acc[4][4] = {};
    for (int k0 = 0; k0 < 512; k0 += 16) {
        float4 av = *(const float4*)&A[(m0 + am) * 512 + k0 + ak];
        float4 bv = *(const float4*)&Xb[(size_t)(k0 + bk) * LEN + l0 + bl];
        __syncthreads();  // previous iteration's reads complete
        As[ak + 0][am] = av.x;
        As[ak + 1][am] = av.y;
        As[ak + 2][am] = av.z;
        As[ak + 3][am] = av.w;
        *(float4*)&Bs[bk][bl] = bv;
        __syncthreads();
#pragma unroll
        for (int kk = 0; kk < 16; ++kk) {
            float4 a4 = *(const float4*)&As[kk][ty << 2];
            float4 b4 = *(const float4*)&Bs[kk][tx << 2];
            float ar[4] = {a4.x, a4.y, a4.z, a4.w};
            float br[4] = {b4.x, b4.y, b4.z, b4.w};
#pragma unroll
            for (int i = 0; i < 4; ++i)
#pragma unroll
                for (int j = 0; j < 4; ++j)
                    acc[i][j] = fmaf(ar[i], br[j], acc[i][j]);
        }
    }
#pragma unroll
    for (int i = 0; i < 4; ++i) {
        float4 o = {acc[i][0], acc[i][1], acc[i][2], acc[i][3]};
        *(float4*)&Yb[(size_t)(m0 + (ty << 2) + i) * LEN + l0 + (tx << 2)] = o;
    }
}

// ---------------------------------------------------------------------------
// Phase A: per (b,n,chunk) local scan from h=0, store chunk-end state.
// states layout: float2 [b*NDIM+n][GCH][SDIM]
// ---------------------------------------------------------------------------
__global__ __launch_bounds__(64) void scan_states(const float* __restrict__ dAr,
                                                  const float* __restrict__ dAi,
                                                  const float* __restrict__ x,
                                                  float* __restrict__ states) {
    const int id = blockIdx.x;            // ((b*NDIM+n)*GCH + k)
    const int k  = id & (GCH - 1);
    const int n  = (id >> 4) & (NDIM - 1);
    const int b  = id >> 13;
    const int s  = threadIdx.x;
    const float a = dAr[n * SDIM + s], w = dAi[n * SDIM + s];
    const float ea = __expf(a);
    const float zr = ea * __cosf(w), zi = ea * __sinf(w);
    const float* xp = x + (((size_t)b * NDIM + n) * LEN) + k * TCH;

    __shared__ __align__(16) float tile[256];
    float hr = 0.f, hi = 0.f;
    for (int t0 = 0; t0 < TCH; t0 += 256) {
        __syncthreads();
        *(float4*)&tile[s * 4] = *(const float4*)&xp[t0 + s * 4];
        __syncthreads();
#pragma unroll 16
        for (int tt = 0; tt < 256; ++tt) {
            float xv  = tile[tt];
            float nhr = fmaf(zr, hr, fmaf(-zi, hi, xv));
            float nhi = fmaf(zi, hr, zr * hi);
            hr = nhr; hi = nhi;
        }
    }
    ((float2*)states)[(size_t)id * SDIM + s] = make_float2(hr, hi);
}

// ---------------------------------------------------------------------------
// Phase B: sequential prefix over chunks per (b,n,s).
// In-place: states[k] (local end) -> H_before[k]. z^T via closed form.
// ---------------------------------------------------------------------------
__global__ __launch_bounds__(256) void scan_combine(const float* __restrict__ dAr,
                                                    const float* __restrict__ dAi,
                                                    float* __restrict__ states) {
    const int tid = blockIdx.x * 256 + threadIdx.x;  // (b*NDIM+n)*SDIM + s
    const int s  = tid & (SDIM - 1);
    const int bn = tid >> 6;
    const int n  = bn & (NDIM - 1);
    const float a = dAr[n * SDIM + s], w = dAi[n * SDIM + s];
    const float eaT = expf(a * (float)TCH);
    float sT, cT;
    sincosf(w * (float)TCH, &sT, &cT);
    const float zTr = eaT * cT, zTi = eaT * sT;
    float2* st = (float2*)states;
    const size_t base = (size_t)bn * GCH * SDIM + s;
    float Hr = 0.f, Hi = 0.f;
    for (int k = 0; k < GCH; ++k) {
        float2 le = st[base + (size_t)k * SDIM];
        st[base + (size_t)k * SDIM] = make_float2(Hr, Hi);
        float nHr = fmaf(zTr, Hr, fmaf(-zTi, Hi, le.x));
        float nHi = fmaf(zTi, Hr, fmaf(zTr, Hi, le.y));
        Hr = nHr; Hi = nHi;
    }
}

// ---------------------------------------------------------------------------
// Phase C: per (b,n,chunk) scan from H_before, emit y (in-place over x).
// Per 32 steps: lanes write E*Re(h) into cmat[tt][s] (stride 65, 2-way max),
// then transpose-reduce over s, combine halves with shfl_xor(32).
// ---------------------------------------------------------------------------
__global__ __launch_bounds__(64) void scan_out(const float* __restrict__ dAr,
                                               const float* __restrict__ dAi,
                                               const float* __restrict__ E,
                                               const float* __restrict__ states,
                                               float* __restrict__ xy) {
    const int id   = blockIdx.x;
    const int k    = id & (GCH - 1);
    const int n    = (id >> 4) & (NDIM - 1);
    const int b    = id >> 13;
    const int lane = threadIdx.x;  // = s
    const float a = dAr[n * SDIM + lane], w = dAi[n * SDIM + lane];
    const float ea = __expf(a);
    const float zr = ea * __cosf(w), zi = ea * __sinf(w);
    const float Ew = E[n * SDIM + lane];
    float2 H = ((const float2*)states)[(size_t)id * SDIM + lane];
    float hr = H.x, hi = H.y;
    float* xp = xy + (((size_t)b * NDIM + n) * LEN) + k * TCH;

    __shared__ __align__(16) float tile[256];
    __shared__ float cmat[32 * 65];

    for (int t0 = 0; t0 < TCH; t0 += 32) {
        if ((t0 & 255) == 0) {
            __syncthreads();
            *(float4*)&tile[lane * 4] = *(const float4*)&xp[t0 + lane * 4];
            __syncthreads();
        }
        const int tb = t0 & 255;
#pragma unroll
        for (int tt = 0; tt < 32; ++tt) {
            float xv  = tile[tb + tt];
            float nhr = fmaf(zr, hr, fmaf(-zi, hi, xv));
            float nhi = fmaf(zi, hr, zr * hi);
            hr = nhr; hi = nhi;
            cmat[tt * 65 + lane] = Ew * hr;
        }
        __syncthreads();
        // lane j<32: row j, s 0..31 ; lane j>=32: row j-32, s 32..63
        const int row = lane & 31, sbase = (lane >> 5) << 5;
        float acc = 0.f;
#pragma unroll
        for (int i = 0; i < 32; ++i) acc += cmat[row * 65 + sbase + i];
        acc += __shfl_xor(acc, 32, 64);
        if (lane < 32) xp[t0 + lane] = acc;
        __syncthreads();
    }
}

// ---------------------------------------------------------------------------
extern "C" void kernel_launch(void* const* d_in, const int* in_sizes, int n_in,
                              void* d_out, int out_size, void* d_ws, size_t ws_size,
                              hipStream_t stream) {
    const float* input = (const float*)d_in[0];  // [B, C, L]
    const float* dAr   = (const float*)d_in[1];  // [N, S]
    const float* dAi   = (const float*)d_in[2];  // [N, S]
    const float* Bm    = (const float*)d_in[3];  // [N, C]
    const float* Cm    = (const float*)d_in[4];  // [C, N]
    const float* E     = (const float*)d_in[5];  // [N, S]
    float* out = (float*)d_out;

    float* wx  = (float*)d_ws;                         // x then y in-place: B*N*L floats
    float* wst = wx + (size_t)BSZ * NDIM * LEN;        // states: B*N*GCH*S*2 floats

    // 1) input projection: x = Bm @ input  (per batch)
    gemm512<<<dim3(LEN / 64, NDIM / 64, BSZ), 256, 0, stream>>>(Bm, input, wx);
    // 2) chunk-local end states
    scan_states<<<BSZ * NDIM * GCH, 64, 0, stream>>>(dAr, dAi, wx, wst);
    // 3) chunk prefix combine
    scan_combine<<<(BSZ * NDIM * SDIM) / 256, 256, 0, stream>>>(dAr, dAi, wst);
    // 4) emit y in-place over x
    scan_out<<<BSZ * NDIM * GCH, 64, 0, stream>>>(dAr, dAi, E, wst, wx);
    // 5) output projection: out = Cm @ y  (per batch)
    gemm512<<<dim3(LEN / 64, CDIM / 64, BSZ), 256, 0, stream>>>(Cm, wx, out);
}

// Round 2
// 590.565 us; speedup vs baseline: 1.4911x; 1.4911x over previous
//
#include <hip/hip_runtime.h>
#include <hip/hip_bf16.h>

typedef unsigned short u16;
typedef __attribute__((ext_vector_type(8))) short short8;
typedef __attribute__((ext_vector_type(4))) float floatx4;

#define BSZ   4
#define CDIM  512
#define NDIM  512
#define SDIM  64
#define LEN   8192
#define GCH   16
#define TCH   (LEN / GCH)

__device__ __forceinline__ u16 f2bf(float x) {
    unsigned int u = __float_as_uint(x);
    unsigned int r = (u + 0x7FFFu + ((u >> 16) & 1u)) >> 16;
    return (u16)r;
}
__device__ __forceinline__ float bf2f(u16 h) {
    return __uint_as_float(((unsigned int)h) << 16);
}

#define GLL16(g, l)                                                          \
    __builtin_amdgcn_global_load_lds(                                        \
        (const __attribute__((address_space(1))) unsigned int*)(g),          \
        (__attribute__((address_space(3))) unsigned int*)(l), 16, 0, 0)

// ---------------------------------------------------------------------------
// Split fp32 -> (hi,lo) bf16, same layout. n multiple of 1024.
// ---------------------------------------------------------------------------
__global__ __launch_bounds__(256) void convert_split(const float* __restrict__ src,
                                                     u16* __restrict__ hi,
                                                     u16* __restrict__ lo) {
    const int i = (blockIdx.x * 256 + threadIdx.x) * 4;
    float4 v = *(const float4*)&src[i];
    float f[4] = {v.x, v.y, v.z, v.w};
    ushort4 h, l;
    u16* hp = (u16*)&h; u16* lp = (u16*)&l;
#pragma unroll
    for (int q = 0; q < 4; ++q) {
        u16 hb = f2bf(f[q]);
        hp[q] = hb;
        lp[q] = f2bf(f[q] - bf2f(hb));
    }
    *(ushort4*)&hi[i] = h;
    *(ushort4*)&lo[i] = l;
}

// ---------------------------------------------------------------------------
// Transposed split: src [B][R=512][L=8192] fp32 -> dhi/dlo [B][L][512] bf16.
// 64x64 LDS tile, coalesced both sides.
// ---------------------------------------------------------------------------
__global__ __launch_bounds__(256) void transpose_split(const float* __restrict__ src,
                                                       u16* __restrict__ dhi,
                                                       u16* __restrict__ dlo) {
    __shared__ float tile[64][65];
    const int b  = blockIdx.z;
    const int r0 = blockIdx.y * 64;   // over 512 rows
    const int c0 = blockIdx.x * 64;   // over 8192 cols
    const int t  = threadIdx.x;
    const float* s = src + (size_t)b * 512 * 8192;
#pragma unroll
    for (int p = 0; p < 4; ++p) {
        int r = (t >> 4) + p * 16;
        float4 v = *(const float4*)&s[(size_t)(r0 + r) * 8192 + c0 + (t & 15) * 4];
        tile[r][(t & 15) * 4 + 0] = v.x;
        tile[r][(t & 15) * 4 + 1] = v.y;
        tile[r][(t & 15) * 4 + 2] = v.z;
        tile[r][(t & 15) * 4 + 3] = v.w;
    }
    __syncthreads();
#pragma unroll
    for (int p = 0; p < 4; ++p) {
        int i  = (t >> 4) + p * 16;   // l offset within tile
        int cb = (t & 15) * 4;        // c offset within tile
        ushort4 h, l;
        u16* hp = (u16*)&h; u16* lp = (u16*)&l;
#pragma unroll
        for (int q = 0; q < 4; ++q) {
            float x = tile[cb + q][i];
            u16 hb = f2bf(x);
            hp[q] = hb;
            lp[q] = f2bf(x - bf2f(hb));
        }
        size_t o = ((size_t)b * 8192 + c0 + i) * 512 + r0 + cb;
        *(ushort4*)&dhi[o] = h;
        *(ushort4*)&dlo[o] = l;
    }
}

// ---------------------------------------------------------------------------
// Split-bf16 MFMA GEMM: Y[b][m][l] = sum_k A[m][k] * Xt[b][l][k]
// A: 512x512 (hi/lo), Xt: [B][8192][512] (hi/lo), Y fp32 [B][512][8192].
// m97 structure: 128x128 tile, BK=32, 16x16x32 bf16 MFMA, global_load_lds(16B).
// 3 split phases: Ahi*Xhi + Ahi*Xlo + Alo*Xhi.
// ---------------------------------------------------------------------------
__global__ __launch_bounds__(256) void gemm_mfma(const u16* __restrict__ Ahi,
                                                 const u16* __restrict__ Alo,
                                                 const u16* __restrict__ Xhi,
                                                 const u16* __restrict__ Xlo,
                                                 float* __restrict__ Y) {
    __shared__ u16 As[128 * 32];
    __shared__ u16 Xs[128 * 32];
    const int b    = blockIdx.z;
    const int m0   = blockIdx.y * 128;
    const int l0   = blockIdx.x * 128;
    const int t    = threadIdx.x;
    const int w    = t >> 6;
    const int lane = t & 63;
    const int mq   = (w >> 1) * 64;
    const int lq   = (w & 1) * 64;

    const u16* Xb_hi = Xhi + (size_t)b * 8192 * 512;
    const u16* Xb_lo = Xlo + (size_t)b * 8192 * 512;

    // staging: wave w covers rows [32w, 32w+32); instr i covers 16 rows.
    const size_t a_off = (size_t)(m0 + 32 * w + (lane >> 2)) * 512 + (lane & 3) * 8;
    const size_t x_off = (size_t)(l0 + 32 * w + (lane >> 2)) * 512 + (lane & 3) * 8;
    u16* AsW = As + w * 1024;   // wave-uniform LDS base (32 rows * 32 elems)
    u16* XsW = Xs + w * 1024;

    floatx4 acc[4][4];
#pragma unroll
    for (int i = 0; i < 4; ++i)
#pragma unroll
        for (int j = 0; j < 4; ++j) acc[i][j] = (floatx4)0.f;

    const int fr = lane & 15;
    const int fk = (lane >> 4) * 8;

#pragma unroll
    for (int p = 0; p < 3; ++p) {
        const u16* Ap = (p == 2) ? Alo : Ahi;
        const u16* Xp = (p == 1) ? Xb_lo : Xb_hi;
        for (int k0 = 0; k0 < 512; k0 += 32) {
            __syncthreads();
            GLL16(Ap + a_off + k0, AsW);
            GLL16(Ap + a_off + 16 * 512 + k0, AsW + 512);
            GLL16(Xp + x_off + k0, XsW);
            GLL16(Xp + x_off + 16 * 512 + k0, XsW + 512);
            __syncthreads();
            short8 af[4], bf[4];
#pragma unroll
            for (int i = 0; i < 4; ++i)
                af[i] = *(const short8*)&As[(mq + i * 16 + fr) * 32 + fk];
#pragma unroll
            for (int j = 0; j < 4; ++j)
                bf[j] = *(const short8*)&Xs[(lq + j * 16 + fr) * 32 + fk];
#pragma unroll
            for (int i = 0; i < 4; ++i)
#pragma unroll
                for (int j = 0; j < 4; ++j)
                    acc[i][j] = __builtin_amdgcn_mfma_f32_16x16x32_bf16(
                        af[i], bf[j], acc[i][j], 0, 0, 0);
        }
    }

    float* Yb = Y + (size_t)b * 512 * 8192;
#pragma unroll
    for (int i = 0; i < 4; ++i)
#pragma unroll
        for (int j = 0; j < 4; ++j)
#pragma unroll
            for (int r = 0; r < 4; ++r) {
                int mg = m0 + mq + i * 16 + (lane >> 4) * 4 + r;
                int lg = l0 + lq + j * 16 + (lane & 15);
                Yb[(size_t)mg * 8192 + lg] = acc[i][j][r];
            }
}

// ---------------------------------------------------------------------------
// Phase A: per (b,n,chunk) local scan from h=0, store chunk-end state.
// ---------------------------------------------------------------------------
__global__ __launch_bounds__(64) void scan_states(const float* __restrict__ dAr,
                                                  const float* __restrict__ dAi,
                                                  const float* __restrict__ x,
                                                  float* __restrict__ states) {
    const int id = blockIdx.x;
    const int k  = id & (GCH - 1);
    const int n  = (id >> 4) & (NDIM - 1);
    const int b  = id >> 13;
    const int s  = threadIdx.x;
    const float a = dAr[n * SDIM + s], w = dAi[n * SDIM + s];
    const float ea = __expf(a);
    const float zr = ea * __cosf(w), zi = ea * __sinf(w);
    const float* xp = x + (((size_t)b * NDIM + n) * LEN) + k * TCH;

    __shared__ __align__(16) float tile[256];
    float hr = 0.f, hi = 0.f;
    for (int t0 = 0; t0 < TCH; t0 += 256) {
        __syncthreads();
        *(float4*)&tile[s * 4] = *(const float4*)&xp[t0 + s * 4];
        __syncthreads();
#pragma unroll 16
        for (int tt = 0; tt < 256; ++tt) {
            float xv  = tile[tt];
            float nhr = fmaf(zr, hr, fmaf(-zi, hi, xv));
            float nhi = fmaf(zi, hr, zr * hi);
            hr = nhr; hi = nhi;
        }
    }
    ((float2*)states)[(size_t)id * SDIM + s] = make_float2(hr, hi);
}

// ---------------------------------------------------------------------------
// Phase B: sequential prefix over chunks per (b,n,s).
// ---------------------------------------------------------------------------
__global__ __launch_bounds__(256) void scan_combine(const float* __restrict__ dAr,
                                                    const float* __restrict__ dAi,
                                                    float* __restrict__ states) {
    const int tid = blockIdx.x * 256 + threadIdx.x;
    const int s  = tid & (SDIM - 1);
    const int bn = tid >> 6;
    const int n  = bn & (NDIM - 1);
    const float a = dAr[n * SDIM + s], w = dAi[n * SDIM + s];
    const float eaT = expf(a * (float)TCH);
    float sT, cT;
    sincosf(w * (float)TCH, &sT, &cT);
    const float zTr = eaT * cT, zTi = eaT * sT;
    float2* st = (float2*)states;
    const size_t base = (size_t)bn * GCH * SDIM + s;
    float Hr = 0.f, Hi = 0.f;
    for (int k = 0; k < GCH; ++k) {
        float2 le = st[base + (size_t)k * SDIM];
        st[base + (size_t)k * SDIM] = make_float2(Hr, Hi);
        float nHr = fmaf(zTr, Hr, fmaf(-zTi, Hi, le.x));
        float nHi = fmaf(zTi, Hr, fmaf(zTr, Hi, le.y));
        Hr = nHr; Hi = nHi;
    }
}

// ---------------------------------------------------------------------------
// Phase C: per (b,n,chunk) scan from H_before, emit y (in-place over x).
// ---------------------------------------------------------------------------
__global__ __launch_bounds__(64) void scan_out(const float* __restrict__ dAr,
                                               const float* __restrict__ dAi,
                                               const float* __restrict__ E,
                                               const float* __restrict__ states,
                                               float* __restrict__ xy) {
    const int id   = blockIdx.x;
    const int k    = id & (GCH - 1);
    const int n    = (id >> 4) & (NDIM - 1);
    const int b    = id >> 13;
    const int lane = threadIdx.x;
    const float a = dAr[n * SDIM + lane], w = dAi[n * SDIM + lane];
    const float ea = __expf(a);
    const float zr = ea * __cosf(w), zi = ea * __sinf(w);
    const float Ew = E[n * SDIM + lane];
    float2 H = ((const float2*)states)[(size_t)id * SDIM + lane];
    float hr = H.x, hi = H.y;
    float* xp = xy + (((size_t)b * NDIM + n) * LEN) + k * TCH;

    __shared__ __align__(16) float tile[256];
    __shared__ float cmat[32 * 65];

    for (int t0 = 0; t0 < TCH; t0 += 32) {
        if ((t0 & 255) == 0) {
            __syncthreads();
            *(float4*)&tile[lane * 4] = *(const float4*)&xp[t0 + lane * 4];
            __syncthreads();
        }
        const int tb = t0 & 255;
#pragma unroll
        for (int tt = 0; tt < 32; ++tt) {
            float xv  = tile[tb + tt];
            float nhr = fmaf(zr, hr, fmaf(-zi, hi, xv));
            float nhi = fmaf(zi, hr, zr * hi);
            hr = nhr; hi = nhi;
            cmat[tt * 65 + lane] = Ew * hr;
        }
        __syncthreads();
        const int row = lane & 31, sbase = (lane >> 5) << 5;
        float acc = 0.f;
#pragma unroll
        for (int i = 0; i < 32; ++i) acc += cmat[row * 65 + sbase + i];
        acc += __shfl_xor(acc, 32, 64);
        if (lane < 32) xp[t0 + lane] = acc;
        __syncthreads();
    }
}

// ---------------------------------------------------------------------------
extern "C" void kernel_launch(void* const* d_in, const int* in_sizes, int n_in,
                              void* d_out, int out_size, void* d_ws, size_t ws_size,
                              hipStream_t stream) {
    const float* input = (const float*)d_in[0];  // [B, C, L]
    const float* dAr   = (const float*)d_in[1];
    const float* dAi   = (const float*)d_in[2];
    const float* Bm    = (const float*)d_in[3];  // [N, C]
    const float* Cm    = (const float*)d_in[4];  // [C, N]
    const float* E     = (const float*)d_in[5];
    float* out = (float*)d_out;

    char* ws = (char*)d_ws;
    float* wx  = (float*)ws;                       // 64 MiB: x then y in-place
    u16* xthi  = (u16*)(ws + 67108864);            // 32 MiB
    u16* xtlo  = (u16*)(ws + 100663296);           // 32 MiB
    u16* wbhi  = (u16*)(ws + 134217728);
    u16* wblo  = (u16*)(ws + 134742016);
    u16* wchi  = (u16*)(ws + 135266304);
    u16* wclo  = (u16*)(ws + 135790592);
    float* wst = (float*)(ws + 67108864);          // states overlay XThi (dead then)

    // weight splits (512*512 = 262144 elems, 4/thread)
    convert_split<<<256, 256, 0, stream>>>(Bm, wbhi, wblo);
    convert_split<<<256, 256, 0, stream>>>(Cm, wchi, wclo);
    // input -> transposed hi/lo
    transpose_split<<<dim3(128, 8, BSZ), 256, 0, stream>>>(input, xthi, xtlo);
    // x = Bm @ input
    gemm_mfma<<<dim3(64, 4, BSZ), 256, 0, stream>>>(wbhi, wblo, xthi, xtlo, wx);
    // scan
    scan_states<<<BSZ * NDIM * GCH, 64, 0, stream>>>(dAr, dAi, wx, wst);
    scan_combine<<<(BSZ * NDIM * SDIM) / 256, 256, 0, stream>>>(dAr, dAi, wst);
    scan_out<<<BSZ * NDIM * GCH, 64, 0, stream>>>(dAr, dAi, E, wst, wx);
    // y -> transposed hi/lo (states dead; overlay safe: kernels are stream-ordered)
    transpose_split<<<dim3(128, 8, BSZ), 256, 0, stream>>>(wx, xthi, xtlo);
    // out = Cm @ y
    gemm_mfma<<<dim3(64, 4, BSZ), 256, 0, stream>>>(wchi, wclo, xthi, xtlo, out);
}